// Round 3
// baseline (6001.372 us; speedup 1.0000x reference)
//
#include <hip/hip_runtime.h>
#include <math.h>

// GraphWaveNet forward — Round 3: S^2 precompute + channel-mix-first GCN.
//
// Identity:  W_g * (x @ S) = (W_g * x) @ S   and   (x@S)@S = x @ S^2.
// Per layer: Y_g = W_g * xg (cheap 32x32 mix), then the whole GCN is
//   out = Y0 + bias + sum_s [Y(2s+1)|Y(2s+2)] @ [S_s ; S_s^2]
// run as 3 GEMM groups of K=4096 (2 support slices each), epilogue-fused
// accumulate / residual+BN. No t1/t2 materialization, no accum kernel.
// skip telescopes (last time step only). End head = MFMA.
//
// Workspace (bytes):                          off          size
//   SbfT  (6 x 2048^2 bf16: S0,S1,S2,S0²,S1²,S2² all transposed)
//                                             0            50,331,648
//   skip  f32 (16x256x2048)                   50,331,648   33,554,432
//   bufA  f32 (8x32x13x2048)                  83,886,080   27,262,976
//   bufB  f32                                 111,149,056  27,262,976
//   xg    bf16 (8x32x12x2048)                 138,412,032  12,582,912
//   Y     bf16 (3072 x 4096)                  150,994,944  25,165,824
// total 176,160,768 (== round-2 footprint, proven OK)
// Overlays: adp f32 @Y (startup), Sbf bf16 @bufA (startup),
//           h bf16 @bufA, skipT bf16 @xg, E1bf @SbfT (all post-loop).

#define NNODE 2048
#define NLAYER 8
#define SSTR ((size_t)NNODE * NNODE)

#define OFF_ST   0UL
#define OFF_SKIP 50331648UL
#define OFF_BUFA 83886080UL
#define OFF_BUFB 111149056UL
#define OFF_XG   138412032UL
#define OFF_Y    150994944UL

typedef unsigned short u16;
typedef __attribute__((ext_vector_type(8))) short bf16x8;
typedef __attribute__((ext_vector_type(4))) float f32x4;

__device__ __forceinline__ u16 f2bf(float f) {
    unsigned u = __builtin_bit_cast(unsigned, f);
    u += 0x7fffu + ((u >> 16) & 1u);   // round-to-nearest-even
    return (u16)(u >> 16);
}
__device__ __forceinline__ float bf2f(u16 h) {
    unsigned u = ((unsigned)h) << 16;
    return __builtin_bit_cast(float, u);
}

__device__ __forceinline__ void gld16(const void* g, void* l) {
    __builtin_amdgcn_global_load_lds(
        (const __attribute__((address_space(1))) unsigned int*)g,
        (__attribute__((address_space(3))) unsigned int*)l, 16, 0, 0);
}

// ---------------- adp = softmax(relu(nv1 @ nv2), axis=1) ----------------
__global__ __launch_bounds__(256) void k_adp_mm(const float* __restrict__ nv1,
                                                const float* __restrict__ nv2,
                                                float* __restrict__ P) {
    int v = blockIdx.y;
    int w = blockIdx.x * 256 + threadIdx.x;
    float acc = 0.f;
#pragma unroll
    for (int k = 0; k < 10; ++k) acc += nv1[v * 10 + k] * nv2[k * NNODE + w];
    P[(size_t)v * NNODE + w] = acc;
}

__global__ __launch_bounds__(256) void k_softmax(float* __restrict__ P) {
    int v = blockIdx.x, tid = threadIdx.x;
    float* row = P + (size_t)v * NNODE;
    float m = 0.f;
    for (int w = tid; w < NNODE; w += 256) m = fmaxf(m, fmaxf(row[w], 0.f));
#pragma unroll
    for (int off = 32; off > 0; off >>= 1) m = fmaxf(m, __shfl_down(m, off));
    __shared__ float redm[4];
    __shared__ float reds[4];
    int wave = tid >> 6, lane = tid & 63;
    if (lane == 0) redm[wave] = m;
    __syncthreads();
    m = fmaxf(fmaxf(redm[0], redm[1]), fmaxf(redm[2], redm[3]));
    float s = 0.f;
    for (int w = tid; w < NNODE; w += 256) s += expf(fmaxf(row[w], 0.f) - m);
#pragma unroll
    for (int off = 32; off > 0; off >>= 1) s += __shfl_down(s, off);
    if (lane == 0) reds[wave] = s;
    __syncthreads();
    s = reds[0] + reds[1] + reds[2] + reds[3];
    float inv = 1.f / s;
    for (int w = tid; w < NNODE; w += 256) row[w] = expf(fmaxf(row[w], 0.f) - m) * inv;
}

// ---- supports: write S^T bf16 (slices 0..2) AND straight-cast S bf16 ----
__global__ __launch_bounds__(256) void k_transp(const float* __restrict__ A,
                                                const float* __restrict__ adp,
                                                u16* __restrict__ ST,
                                                u16* __restrict__ Sbf) {
    __shared__ float tile[32][33];
    int s = blockIdx.z;
    const float* src = (s < 2) ? (A + (size_t)s * SSTR) : adp;
    int v0 = blockIdx.y * 32, w0 = blockIdx.x * 32;
    int tx = threadIdx.x & 31, ty = threadIdx.x >> 5;  // 32 x 8
    u16* dst2 = Sbf + (size_t)s * SSTR;
#pragma unroll
    for (int p = 0; p < 4; ++p) {
        float v = src[(size_t)(v0 + ty + p * 8) * NNODE + w0 + tx];
        tile[ty + p * 8][tx] = v;
        dst2[(size_t)(v0 + ty + p * 8) * NNODE + w0 + tx] = f2bf(v);
    }
    __syncthreads();
    u16* dst = ST + (size_t)s * SSTR;
#pragma unroll
    for (int p = 0; p < 4; ++p)
        dst[(size_t)(w0 + ty + p * 8) * NNODE + v0 + tx] = f2bf(tile[tx][ty + p * 8]);
}

// ---- plain bf16 MFMA GEMM (used for S^2): C = A @ B, BT supplied ----
// C[m,n] = sum_k A[m,k]*BT[n,k].  With A=S^T, BT=S: C = (S^2)^T.  128x128, BK=32.
__global__ __launch_bounds__(256) void k_gemm_mfma(
    const u16* __restrict__ A, int lda, size_t asstr,
    const u16* __restrict__ BT, size_t bsstr,
    u16* __restrict__ C, int ldc, size_t csstr, int sbase) {
    __shared__ u16 Asl[128 * 32];
    __shared__ u16 Bsl[128 * 32];
    const int tid = threadIdx.x;
    const int wave = tid >> 6, lane = tid & 63;
    const int sidx = sbase + blockIdx.z;
    const u16* Ab = A + sidx * asstr + (size_t)blockIdx.y * 128 * lda;
    const u16* Bb = BT + sidx * bsstr + (size_t)blockIdx.x * 128 * NNODE;
    const int tr = tid >> 2;
    const int tc = (tid & 3) * 8;
    char* AslB = (char*)Asl + wave * 1024;
    char* BslB = (char*)Bsl + wave * 1024;
    const int wm = (wave & 1) * 64, wn = (wave >> 1) * 64;
    const int fr = lane & 15;
    const int fk = (lane >> 4) * 8;
    f32x4 acc[4][4];
#pragma unroll
    for (int i = 0; i < 4; ++i)
#pragma unroll
        for (int j = 0; j < 4; ++j) acc[i][j] = (f32x4){0.f, 0.f, 0.f, 0.f};

    for (int k0 = 0; k0 < 2048; k0 += 32) {
        gld16(Ab + (size_t)tr * lda + k0 + tc, AslB);
        gld16(Ab + (size_t)(tr + 64) * lda + k0 + tc, AslB + 4096);
        gld16(Bb + (size_t)tr * NNODE + k0 + tc, BslB);
        gld16(Bb + (size_t)(tr + 64) * NNODE + k0 + tc, BslB + 4096);
        __syncthreads();
        bf16x8 af[4], bf[4];
#pragma unroll
        for (int i = 0; i < 4; ++i)
            af[i] = *(const bf16x8*)&Asl[(wm + i * 16 + fr) * 32 + fk];
#pragma unroll
        for (int j = 0; j < 4; ++j)
            bf[j] = *(const bf16x8*)&Bsl[(wn + j * 16 + fr) * 32 + fk];
#pragma unroll
        for (int i = 0; i < 4; ++i)
#pragma unroll
            for (int j = 0; j < 4; ++j)
                acc[i][j] = __builtin_amdgcn_mfma_f32_16x16x32_bf16(af[i], bf[j], acc[i][j], 0, 0, 0);
        __syncthreads();
    }
    u16* Cb = C + sidx * csstr + (size_t)(blockIdx.y * 128 + wm) * ldc + blockIdx.x * 128 + wn;
    const int orow = (lane >> 4) * 4;
#pragma unroll
    for (int i = 0; i < 4; ++i)
#pragma unroll
        for (int j = 0; j < 4; ++j)
#pragma unroll
            for (int r = 0; r < 4; ++r)
                Cb[(size_t)(i * 16 + orow + r) * ldc + j * 16 + fr] = f2bf(acc[i][j][r]);
}

// ---------------- start conv: pad t by 1, 2 -> 32 channels ----------------
__global__ __launch_bounds__(256) void k_start(const float* __restrict__ xin,
                                               const float* __restrict__ sw,
                                               const float* __restrict__ sb,
                                               float* __restrict__ out, int b0) {
    int n = blockIdx.x * 256 + threadIdx.x;
    int t = blockIdx.y;
    int bl = blockIdx.z;
    int b = b0 + bl;
    float x0 = 0.f, x1 = 0.f;
    if (t > 0) {
        x0 = xin[((size_t)(b * 2 + 0) * NNODE + n) * 12 + (t - 1)];
        x1 = xin[((size_t)(b * 2 + 1) * NNODE + n) * 12 + (t - 1)];
    }
#pragma unroll
    for (int co = 0; co < 32; ++co) {
        float v = sw[co * 2 + 0] * x0 + sw[co * 2 + 1] * x1 + sb[co];
        out[((size_t)(bl * 32 + co) * 13 + t) * NNODE + n] = v;
    }
}

// ------- fused dilated filter/gate conv + tanh*sigmoid -> bf16 xg -------
__global__ __launch_bounds__(256) void k_gate(const float* __restrict__ cur,
                                              u16* __restrict__ xg, int T, int Tn, int d,
                                              const float* __restrict__ fw,
                                              const float* __restrict__ fb,
                                              const float* __restrict__ gw,
                                              const float* __restrict__ gb) {
    __shared__ float4 wp[1024];  // [ci*32+co] = {fw0, fw1, gw0, gw1}
    int tid = threadIdx.x;
#pragma unroll
    for (int u = 0; u < 4; ++u) {
        int idx = tid + u * 256;
        int ci = idx >> 5, co = idx & 31;
        wp[idx] = make_float4(fw[co * 64 + ci * 2], fw[co * 64 + ci * 2 + 1],
                              gw[co * 64 + ci * 2], gw[co * 64 + ci * 2 + 1]);
    }
    __syncthreads();
    int n = blockIdx.x * 512 + tid;
    int t = blockIdx.y;
    int bl = blockIdx.z;
    float f0[32], f1[32], g0[32], g1[32];
#pragma unroll
    for (int co = 0; co < 32; ++co) { f0[co] = 0.f; f1[co] = 0.f; g0[co] = 0.f; g1[co] = 0.f; }
    for (int ci = 0; ci < 32; ++ci) {
        size_t ba = ((size_t)(bl * 32 + ci) * T + t) * NNODE + n;
        size_t bb = ((size_t)(bl * 32 + ci) * T + t + d) * NNODE + n;
        float xa0 = cur[ba], xa1 = cur[ba + 256];
        float xb0 = cur[bb], xb1 = cur[bb + 256];
#pragma unroll
        for (int co = 0; co < 32; ++co) {
            float4 w = wp[ci * 32 + co];
            f0[co] += w.x * xa0 + w.y * xb0;
            f1[co] += w.x * xa1 + w.y * xb1;
            g0[co] += w.z * xa0 + w.w * xb0;
            g1[co] += w.z * xa1 + w.w * xb1;
        }
    }
#pragma unroll
    for (int co = 0; co < 32; ++co) {
        float fbv = fb[co], gbv = gb[co];
        float a0 = tanhf(f0[co] + fbv) * (1.f / (1.f + expf(-(g0[co] + gbv))));
        float a1 = tanhf(f1[co] + fbv) * (1.f / (1.f + expf(-(g1[co] + gbv))));
        size_t o = ((size_t)(bl * 32 + co) * Tn + t) * NNODE + n;
        xg[o] = f2bf(a0);
        xg[o + 256] = f2bf(a1);
    }
}

// ---- skip conv, last time step only; accumulates across layers (f32) ----
__global__ __launch_bounds__(256) void k_skip(const u16* __restrict__ xg,
                                              float* __restrict__ skip, int Tn,
                                              const float* __restrict__ sw,
                                              const float* __restrict__ sb, int b0, int init) {
    __shared__ float wl[256];  // 8 sc rows x 32 ci
    int tid = threadIdx.x;
    int sc0 = blockIdx.y * 8;
    wl[tid] = sw[sc0 * 32 + tid];
    __syncthreads();
    int n = blockIdx.x * 256 + tid;
    int bl = blockIdx.z;
    float acc[8];
#pragma unroll
    for (int j = 0; j < 8; ++j) acc[j] = 0.f;
    for (int ci = 0; ci < 32; ci += 4) {
        float v0 = bf2f(xg[((size_t)(bl * 32 + ci + 0) * Tn + (Tn - 1)) * NNODE + n]);
        float v1 = bf2f(xg[((size_t)(bl * 32 + ci + 1) * Tn + (Tn - 1)) * NNODE + n]);
        float v2 = bf2f(xg[((size_t)(bl * 32 + ci + 2) * Tn + (Tn - 1)) * NNODE + n]);
        float v3 = bf2f(xg[((size_t)(bl * 32 + ci + 3) * Tn + (Tn - 1)) * NNODE + n]);
#pragma unroll
        for (int j = 0; j < 8; ++j) {
            float4 w = *(const float4*)&wl[j * 32 + ci];
            acc[j] += w.x * v0 + w.y * v1 + w.z * v2 + w.w * v3;
        }
    }
    int b = b0 + bl;
#pragma unroll
    for (int j = 0; j < 8; ++j) {
        size_t o = ((size_t)(b * 256) + sc0 + j) * NNODE + n;
        float val = acc[j] + sb[sc0 + j];
        if (init) skip[o] = val;
        else skip[o] += val;
    }
}

// ---- channel pre-mix: Y slice s = W[:, cs+.]*xg  (bf16); optionally
//      nxt = W[:, c0+.]*xg + gcn bias (f32, the GCN accumulator init) ----
__global__ __launch_bounds__(256) void k_Y(const u16* __restrict__ xg,
                                           const float* __restrict__ gcnw,
                                           const float* __restrict__ gcnb,
                                           float* __restrict__ nxt,
                                           u16* __restrict__ Y,
                                           int c0, int c1, int c2, int donxt, int Tn) {
    __shared__ float wl[3][32][32];  // [g][ci][co]
    int tid = threadIdx.x;
#pragma unroll
    for (int u = 0; u < 4; ++u) {
        int idx = tid + u * 256;
        int ci = idx >> 5, co = idx & 31;
        wl[0][ci][co] = gcnw[co * 224 + c0 + ci];
        wl[1][ci][co] = gcnw[co * 224 + c1 + ci];
        wl[2][ci][co] = gcnw[co * 224 + c2 + ci];
    }
    __syncthreads();
    int n = blockIdx.x * 512 + tid;  // n and n+256
    int t = blockIdx.y, bl = blockIdx.z;
    float x0[32], x1[32];
#pragma unroll
    for (int ci = 0; ci < 32; ++ci) {
        size_t base = ((size_t)(bl * 32 + ci) * Tn + t) * NNODE + n;
        x0[ci] = bf2f(xg[base]);
        x1[ci] = bf2f(xg[base + 256]);
    }
    if (donxt) {
#pragma unroll
        for (int co = 0; co < 32; ++co) {
            float a0 = gcnb[co], a1 = gcnb[co];
#pragma unroll
            for (int ci = 0; ci < 32; ++ci) {
                float w = wl[0][ci][co];
                a0 += w * x0[ci];
                a1 += w * x1[ci];
            }
            size_t o = ((size_t)(bl * 32 + co) * Tn + t) * NNODE + n;
            nxt[o] = a0;
            nxt[o + 256] = a1;
        }
    }
#pragma unroll
    for (int s = 1; s < 3; ++s) {
#pragma unroll
        for (int co = 0; co < 32; ++co) {
            float a0 = 0.f, a1 = 0.f;
#pragma unroll
            for (int ci = 0; ci < 32; ++ci) {
                float w = wl[s][ci][co];
                a0 += w * x0[ci];
                a1 += w * x1[ci];
            }
            size_t o = ((size_t)(bl * 32 + co) * Tn + t) * 4096 + (size_t)(s - 1) * 2048 + n;
            Y[o] = f2bf(a0);
            Y[o + 256] = f2bf(a1);
        }
    }
}

// ---- GCN group GEMM: out (+)= Y[Mx4096] @ [S_a ; S_b]; final: +resid, BN ----
__global__ __launch_bounds__(256) void k_gemm_gcn(
    const u16* __restrict__ Yb, const u16* __restrict__ ST, int bs0, int bs1,
    float* __restrict__ outp, const float* __restrict__ resid,
    int Tn, int dd, int finalf,
    const float* __restrict__ bng, const float* __restrict__ bnb,
    const float* __restrict__ bnm, const float* __restrict__ bnv) {
    __shared__ u16 Asl[128 * 32];
    __shared__ u16 Bsl[128 * 32];
    const int tid = threadIdx.x;
    const int wave = tid >> 6, lane = tid & 63;
    const int m0 = blockIdx.y * 128;
    const int n0 = blockIdx.x * 128;
    const int tr = tid >> 2;
    const int tc = (tid & 3) * 8;
    char* AslB = (char*)Asl + wave * 1024;
    char* BslB = (char*)Bsl + wave * 1024;
    const int wm = (wave & 1) * 64, wn = (wave >> 1) * 64;
    const int fr = lane & 15;
    const int fk = (lane >> 4) * 8;
    f32x4 acc[4][4];
#pragma unroll
    for (int i = 0; i < 4; ++i)
#pragma unroll
        for (int j = 0; j < 4; ++j) acc[i][j] = (f32x4){0.f, 0.f, 0.f, 0.f};

#pragma unroll
    for (int half = 0; half < 2; ++half) {
        const u16* Ab = Yb + (size_t)m0 * 4096 + half * 2048;
        const u16* Bb = ST + (size_t)(half ? bs1 : bs0) * SSTR + (size_t)n0 * NNODE;
        for (int k0 = 0; k0 < 2048; k0 += 32) {
            gld16(Ab + (size_t)tr * 4096 + k0 + tc, AslB);
            gld16(Ab + (size_t)(tr + 64) * 4096 + k0 + tc, AslB + 4096);
            gld16(Bb + (size_t)tr * NNODE + k0 + tc, BslB);
            gld16(Bb + (size_t)(tr + 64) * NNODE + k0 + tc, BslB + 4096);
            __syncthreads();
            bf16x8 af[4], bf[4];
#pragma unroll
            for (int i = 0; i < 4; ++i)
                af[i] = *(const bf16x8*)&Asl[(wm + i * 16 + fr) * 32 + fk];
#pragma unroll
            for (int j = 0; j < 4; ++j)
                bf[j] = *(const bf16x8*)&Bsl[(wn + j * 16 + fr) * 32 + fk];
#pragma unroll
            for (int i = 0; i < 4; ++i)
#pragma unroll
                for (int j = 0; j < 4; ++j)
                    acc[i][j] = __builtin_amdgcn_mfma_f32_16x16x32_bf16(af[i], bf[j], acc[i][j], 0, 0, 0);
            __syncthreads();
        }
    }
    const int orow = (lane >> 4) * 4;
#pragma unroll
    for (int i = 0; i < 4; ++i) {
#pragma unroll
        for (int r = 0; r < 4; ++r) {
            int m = m0 + wm + i * 16 + orow + r;
            size_t ob = (size_t)m * NNODE + n0 + wn;
            if (finalf) {
                int mc = m / Tn;
                int tt = m - mc * Tn;
                int c = mc & 31;
                float inv = bng[c] * rsqrtf(bnv[c] + 1e-5f);
                float mu = bnm[c], be = bnb[c];
                size_t rb = ((size_t)mc * (Tn + dd) + tt + dd) * NNODE + n0 + wn;
#pragma unroll
                for (int j = 0; j < 4; ++j) {
                    size_t o = ob + j * 16 + fr;
                    float v = outp[o] + acc[i][j][r] + resid[rb + j * 16 + fr];
                    outp[o] = (v - mu) * inv + be;
                }
            } else {
#pragma unroll
                for (int j = 0; j < 4; ++j) {
                    size_t o = ob + j * 16 + fr;
                    outp[o] += acc[i][j][r];
                }
            }
        }
    }
}

// ---- end head prep: skipT[b][n][sc] = bf16(relu(skip[b][sc][n])) ----
__global__ __launch_bounds__(256) void k_skipT(const float* __restrict__ skip,
                                               u16* __restrict__ skipT) {
    __shared__ float tile[32][33];
    int b = blockIdx.z;
    int n0 = blockIdx.x * 32, c0 = blockIdx.y * 32;
    int tx = threadIdx.x & 31, ty = threadIdx.x >> 5;
#pragma unroll
    for (int p = 0; p < 4; ++p)
        tile[ty + p * 8][tx] = skip[((size_t)b * 256 + c0 + ty + p * 8) * NNODE + n0 + tx];
    __syncthreads();
#pragma unroll
    for (int p = 0; p < 4; ++p)
        skipT[((size_t)b * NNODE + n0 + ty + p * 8) * 256 + c0 + tx] =
            f2bf(fmaxf(tile[tx][ty + p * 8], 0.f));
}

__global__ __launch_bounds__(256) void k_cast(const float* __restrict__ src,
                                              u16* __restrict__ dst) {
    int i = blockIdx.x * 256 + threadIdx.x;
    dst[i] = f2bf(src[i]);
}

// ---- end1 MFMA: h[b][e][n] = relu(E1[e,:] . relu(skip)[b,:,n] + b1[e]) ----
__global__ __launch_bounds__(256) void k_end1m(const u16* __restrict__ E1,
                                               const u16* __restrict__ skT,
                                               const float* __restrict__ bias,
                                               u16* __restrict__ h) {
    __shared__ u16 Asl[128 * 32];
    __shared__ u16 Bsl[128 * 32];
    const int tid = threadIdx.x;
    const int wave = tid >> 6, lane = tid & 63;
    const int b = blockIdx.z;
    const int m0 = blockIdx.y * 128;
    const int n0 = blockIdx.x * 128;
    const int tr = tid >> 2;
    const int tc = (tid & 3) * 8;
    char* AslB = (char*)Asl + wave * 1024;
    char* BslB = (char*)Bsl + wave * 1024;
    const int wm = (wave & 1) * 64, wn = (wave >> 1) * 64;
    const int fr = lane & 15;
    const int fk = (lane >> 4) * 8;
    const u16* Ab = E1 + (size_t)m0 * 256;
    const u16* Bb = skT + ((size_t)b * NNODE + n0) * 256;
    f32x4 acc[4][4];
#pragma unroll
    for (int i = 0; i < 4; ++i)
#pragma unroll
        for (int j = 0; j < 4; ++j) acc[i][j] = (f32x4){0.f, 0.f, 0.f, 0.f};
    for (int k0 = 0; k0 < 256; k0 += 32) {
        gld16(Ab + (size_t)tr * 256 + k0 + tc, AslB);
        gld16(Ab + (size_t)(tr + 64) * 256 + k0 + tc, AslB + 4096);
        gld16(Bb + (size_t)tr * 256 + k0 + tc, BslB);
        gld16(Bb + (size_t)(tr + 64) * 256 + k0 + tc, BslB + 4096);
        __syncthreads();
        bf16x8 af[4], bf[4];
#pragma unroll
        for (int i = 0; i < 4; ++i)
            af[i] = *(const bf16x8*)&Asl[(wm + i * 16 + fr) * 32 + fk];
#pragma unroll
        for (int j = 0; j < 4; ++j)
            bf[j] = *(const bf16x8*)&Bsl[(wn + j * 16 + fr) * 32 + fk];
#pragma unroll
        for (int i = 0; i < 4; ++i)
#pragma unroll
            for (int j = 0; j < 4; ++j)
                acc[i][j] = __builtin_amdgcn_mfma_f32_16x16x32_bf16(af[i], bf[j], acc[i][j], 0, 0, 0);
        __syncthreads();
    }
    const int orow = (lane >> 4) * 4;
#pragma unroll
    for (int i = 0; i < 4; ++i)
#pragma unroll
        for (int r = 0; r < 4; ++r) {
            int m = m0 + wm + i * 16 + orow + r;  // e index, < 512
            float bs = bias[m];
            size_t ob = ((size_t)b * 512 + m) * NNODE + n0 + wn;
#pragma unroll
            for (int j = 0; j < 4; ++j)
                h[ob + j * 16 + fr] = f2bf(fmaxf(acc[i][j][r] + bs, 0.f));
        }
}

__global__ __launch_bounds__(256) void k_end2(const u16* __restrict__ h,
                                              const float* __restrict__ w,
                                              const float* __restrict__ bias,
                                              float* __restrict__ out) {
    __shared__ float wl[512];
    int tid = threadIdx.x;
    int o = blockIdx.y;
    wl[tid] = w[o * 512 + tid];
    wl[tid + 256] = w[o * 512 + tid + 256];
    __syncthreads();
    int n = blockIdx.x * 256 + tid;
    int b = blockIdx.z;
    float acc = 0.f;
    for (int e = 0; e < 512; ++e) acc += wl[e] * bf2f(h[((size_t)(b * 512) + e) * NNODE + n]);
    out[((size_t)(b * 12) + o) * NNODE + n] = acc + bias[o];
}

extern "C" void kernel_launch(void* const* d_in, const int* in_sizes, int n_in,
                              void* d_out, int out_size, void* d_ws, size_t ws_size,
                              hipStream_t stream) {
    const float* x_in = (const float*)d_in[0];
    const float* A    = (const float*)d_in[1];
    const float* nv1  = (const float*)d_in[2];
    const float* nv2  = (const float*)d_in[3];
    const float* fw   = (const float*)d_in[4];
    const float* fb   = (const float*)d_in[5];
    const float* gw   = (const float*)d_in[6];
    const float* gb   = (const float*)d_in[7];
    const float* skw  = (const float*)d_in[8];
    const float* skb  = (const float*)d_in[9];
    const float* gcw  = (const float*)d_in[10];
    const float* gcb  = (const float*)d_in[11];
    const float* bng  = (const float*)d_in[12];
    const float* bnb  = (const float*)d_in[13];
    const float* bnm  = (const float*)d_in[14];
    const float* bnv  = (const float*)d_in[15];
    const float* stw  = (const float*)d_in[16];
    const float* stb  = (const float*)d_in[17];
    const float* e1w  = (const float*)d_in[18];
    const float* e1b  = (const float*)d_in[19];
    const float* e2w  = (const float*)d_in[20];
    const float* e2b  = (const float*)d_in[21];
    (void)in_sizes; (void)n_in; (void)out_size; (void)ws_size;

    char* base = (char*)d_ws;
    u16*   ST   = (u16*)(base + OFF_ST);
    float* skip = (float*)(base + OFF_SKIP);
    float* bufA = (float*)(base + OFF_BUFA);
    float* bufB = (float*)(base + OFF_BUFB);
    u16*   xg   = (u16*)(base + OFF_XG);
    u16*   Y    = (u16*)(base + OFF_Y);
    // startup overlays
    float* adp  = (float*)(base + OFF_Y);
    u16*   Sbf  = (u16*)(base + OFF_BUFA);
    // post-loop overlays
    u16*   h     = (u16*)(base + OFF_BUFA);
    u16*   skipT = (u16*)(base + OFF_XG);
    u16*   E1bf  = (u16*)(base + OFF_ST);

    k_adp_mm<<<dim3(8, 2048), 256, 0, stream>>>(nv1, nv2, adp);
    k_softmax<<<2048, 256, 0, stream>>>(adp);
    k_transp<<<dim3(64, 64, 3), 256, 0, stream>>>(A, adp, ST, Sbf);
    // (S_s^2)^T = S_s^T @ S_s^T; kernel computes sum_k A[m,k]*BT[n,k] with
    // A=S^T, BT=S  ->  C[m,n] = (S^2)^T[m,n].  Slices 3..5.
    k_gemm_mfma<<<dim3(16, 16, 3), 256, 0, stream>>>(
        ST, NNODE, SSTR, Sbf, SSTR, ST + 3 * SSTR, NNODE, SSTR, 0);

    static const int DIL[NLAYER] = {1, 2, 1, 2, 1, 2, 1, 2};
    for (int ch = 0; ch < 2; ++ch) {
        int b0 = ch * 8;
        k_start<<<dim3(8, 13, 8), 256, 0, stream>>>(x_in, stw, stb, bufA, b0);
        float* cur = bufA;
        float* nxt = bufB;
        int T = 13;
        for (int i = 0; i < NLAYER; ++i) {
            int d = DIL[i], Tn = T - d;
            k_gate<<<dim3(4, Tn, 8), 256, 0, stream>>>(cur, xg, T, Tn, d,
                fw + i * 2048, fb + i * 32, gw + i * 2048, gb + i * 32);
            k_skip<<<dim3(8, 32, 8), 256, 0, stream>>>(xg, skip, Tn,
                skw + i * 256 * 32, skb + i * 256, b0, (i == 0) ? 1 : 0);
            if (i == NLAYER - 1) break;  // layer 7's GCN output is dead
            int MB = 2 * Tn;
            const float* gcwi = gcw + i * 32 * 224;
            // group A: g0 -> nxt (init), slices {A0 hop1 (ST0), A0 hop2 (ST3)}
            k_Y<<<dim3(4, Tn, 8), 256, 0, stream>>>(xg, gcwi, gcb + i * 32,
                nxt, Y, 0, 32, 64, 1, Tn);
            k_gemm_gcn<<<dim3(16, MB), 256, 0, stream>>>(Y, ST, 0, 3, nxt,
                cur, Tn, d, 0, bng + i * 32, bnb + i * 32, bnm + i * 32, bnv + i * 32);
            // group B: slices {A1 hop1 (ST1), A1 hop2 (ST4)}
            k_Y<<<dim3(4, Tn, 8), 256, 0, stream>>>(xg, gcwi, gcb + i * 32,
                nullptr, Y, 0, 96, 128, 0, Tn);
            k_gemm_gcn<<<dim3(16, MB), 256, 0, stream>>>(Y, ST, 1, 4, nxt,
                cur, Tn, d, 0, bng + i * 32, bnb + i * 32, bnm + i * 32, bnv + i * 32);
            // group C: slices {adp hop1 (ST2), adp hop2 (ST5)} + resid + BN
            k_Y<<<dim3(4, Tn, 8), 256, 0, stream>>>(xg, gcwi, gcb + i * 32,
                nullptr, Y, 0, 160, 192, 0, Tn);
            k_gemm_gcn<<<dim3(16, MB), 256, 0, stream>>>(Y, ST, 2, 5, nxt,
                cur, Tn, d, 1, bng + i * 32, bnb + i * 32, bnm + i * 32, bnv + i * 32);
            float* tmp = cur; cur = nxt; nxt = tmp;
            T = Tn;
        }
    }
    k_cast<<<512, 256, 0, stream>>>(e1w, E1bf);
    k_skipT<<<dim3(64, 8, 16), 256, 0, stream>>>(skip, skipT);
    k_end1m<<<dim3(16, 4, 16), 256, 0, stream>>>(E1bf, skipT, e1b, h);
    k_end2<<<dim3(8, 12, 16), 256, 0, stream>>>(h, e2w, e2b, (float*)d_out);
}

// Round 4
// 3599.440 us; speedup vs baseline: 1.6673x; 1.6673x over previous
//
#include <hip/hip_runtime.h>
#include <math.h>

// GraphWaveNet forward — Round 4: Z-form GCN (GEMM-first, mix-after) + runtime
// batch-chunk merge.
//
// Identity: x@S, x@S^2 computed directly from xg (A-operand = xg, no pre-mix
// on the GEMM critical path):  Z = xg @ [S_p | S_p^2]  (N=4096 per pass,
// grid 32 x M/128 — 2x round-3's blocks), then k_accum applies the 32x32
// channel mix W_g per group, accumulating into nxt; pass 2 adds resid+BN.
// ST slice order: [S0,S0²,S1,S1²,S2,S2²]^T  -> pass p uses slices 2p,2p+1,
// weight cols 32+64p / 64+64p (group order matches reference concat).
//
// Runtime BL selection: BL=16 (all batches, one chunk) needs exactly 256 MB;
// else BL=8 (two chunks) needs 176,160,768 B (proven in rounds 1-3).
// Layout (BL = batches per chunk):
//   ST    6 x 2048^2 bf16                     @0          50,331,648
//   skip  16x256x2048 f32                     @50,331,648 33,554,432
//   bufA  BL x 32 x 13 x 2048 f32             @83,886,080 BL*3,407,872
//   bufB  same                                 (adjacent)
//   xg    BL x 32 x 12 x 2048 bf16             (adjacent)  BL*1,572,864
//   Z     (BL*32*12) x 4096 bf16               (adjacent)  BL*3,145,728
// Overlays: adp f32 @Z, Sbf bf16 @bufA (startup); h bf16 @bufA(+bufB),
// skipT bf16 @xg(+Z), E1bf @ST (post-loop).

#define NNODE 2048
#define NLAYER 8
#define SSTR ((size_t)NNODE * NNODE)

typedef unsigned short u16;
typedef __attribute__((ext_vector_type(8))) short bf16x8;
typedef __attribute__((ext_vector_type(4))) float f32x4;

__device__ __forceinline__ u16 f2bf(float f) {
    unsigned u = __builtin_bit_cast(unsigned, f);
    u += 0x7fffu + ((u >> 16) & 1u);   // round-to-nearest-even
    return (u16)(u >> 16);
}
__device__ __forceinline__ float bf2f(u16 h) {
    unsigned u = ((unsigned)h) << 16;
    return __builtin_bit_cast(float, u);
}

__device__ __forceinline__ void gld16(const void* g, void* l) {
    __builtin_amdgcn_global_load_lds(
        (const __attribute__((address_space(1))) unsigned int*)g,
        (__attribute__((address_space(3))) unsigned int*)l, 16, 0, 0);
}

// ---------------- adp = softmax(relu(nv1 @ nv2), axis=1) ----------------
__global__ __launch_bounds__(256) void k_adp_mm(const float* __restrict__ nv1,
                                                const float* __restrict__ nv2,
                                                float* __restrict__ P) {
    int v = blockIdx.y;
    int w = blockIdx.x * 256 + threadIdx.x;
    float acc = 0.f;
#pragma unroll
    for (int k = 0; k < 10; ++k) acc += nv1[v * 10 + k] * nv2[k * NNODE + w];
    P[(size_t)v * NNODE + w] = acc;
}

__global__ __launch_bounds__(256) void k_softmax(float* __restrict__ P) {
    int v = blockIdx.x, tid = threadIdx.x;
    float* row = P + (size_t)v * NNODE;
    float m = 0.f;
    for (int w = tid; w < NNODE; w += 256) m = fmaxf(m, fmaxf(row[w], 0.f));
#pragma unroll
    for (int off = 32; off > 0; off >>= 1) m = fmaxf(m, __shfl_down(m, off));
    __shared__ float redm[4];
    __shared__ float reds[4];
    int wave = tid >> 6, lane = tid & 63;
    if (lane == 0) redm[wave] = m;
    __syncthreads();
    m = fmaxf(fmaxf(redm[0], redm[1]), fmaxf(redm[2], redm[3]));
    float s = 0.f;
    for (int w = tid; w < NNODE; w += 256) s += expf(fmaxf(row[w], 0.f) - m);
#pragma unroll
    for (int off = 32; off > 0; off >>= 1) s += __shfl_down(s, off);
    if (lane == 0) reds[wave] = s;
    __syncthreads();
    s = reds[0] + reds[1] + reds[2] + reds[3];
    float inv = 1.f / s;
    for (int w = tid; w < NNODE; w += 256) row[w] = expf(fmaxf(row[w], 0.f) - m) * inv;
}

// ---- supports: S_s^T bf16 -> ST slice 2s; straight-cast S bf16 -> Sbf ----
__global__ __launch_bounds__(256) void k_transp(const float* __restrict__ A,
                                                const float* __restrict__ adp,
                                                u16* __restrict__ ST,
                                                u16* __restrict__ Sbf) {
    __shared__ float tile[32][33];
    int s = blockIdx.z;
    const float* src = (s < 2) ? (A + (size_t)s * SSTR) : adp;
    int v0 = blockIdx.y * 32, w0 = blockIdx.x * 32;
    int tx = threadIdx.x & 31, ty = threadIdx.x >> 5;  // 32 x 8
    u16* dst2 = Sbf + (size_t)s * SSTR;
#pragma unroll
    for (int p = 0; p < 4; ++p) {
        float v = src[(size_t)(v0 + ty + p * 8) * NNODE + w0 + tx];
        tile[ty + p * 8][tx] = v;
        dst2[(size_t)(v0 + ty + p * 8) * NNODE + w0 + tx] = f2bf(v);
    }
    __syncthreads();
    u16* dst = ST + (size_t)(2 * s) * SSTR;
#pragma unroll
    for (int p = 0; p < 4; ++p)
        dst[(size_t)(w0 + ty + p * 8) * NNODE + v0 + tx] = f2bf(tile[tx][ty + p * 8]);
}

// ---- generic bf16 MFMA GEMM (used for S^2): C[m,n] = sum_k A[m,k]*BT[n,k] ----
// With A=S^T, BT=S: C = (S^2)^T.  128x128, BK=32.
__global__ __launch_bounds__(256) void k_gemm_mfma(
    const u16* __restrict__ A, int lda, size_t asstr,
    const u16* __restrict__ BT, size_t bsstr,
    u16* __restrict__ C, int ldc, size_t csstr, int sbase) {
    __shared__ u16 Asl[128 * 32];
    __shared__ u16 Bsl[128 * 32];
    const int tid = threadIdx.x;
    const int wave = tid >> 6, lane = tid & 63;
    const int sidx = sbase + blockIdx.z;
    const u16* Ab = A + sidx * asstr + (size_t)blockIdx.y * 128 * lda;
    const u16* Bb = BT + sidx * bsstr + (size_t)blockIdx.x * 128 * NNODE;
    const int tr = tid >> 2;
    const int tc = (tid & 3) * 8;
    char* AslB = (char*)Asl + wave * 1024;
    char* BslB = (char*)Bsl + wave * 1024;
    const int wm = (wave & 1) * 64, wn = (wave >> 1) * 64;
    const int fr = lane & 15;
    const int fk = (lane >> 4) * 8;
    f32x4 acc[4][4];
#pragma unroll
    for (int i = 0; i < 4; ++i)
#pragma unroll
        for (int j = 0; j < 4; ++j) acc[i][j] = (f32x4){0.f, 0.f, 0.f, 0.f};

    for (int k0 = 0; k0 < 2048; k0 += 32) {
        gld16(Ab + (size_t)tr * lda + k0 + tc, AslB);
        gld16(Ab + (size_t)(tr + 64) * lda + k0 + tc, AslB + 4096);
        gld16(Bb + (size_t)tr * NNODE + k0 + tc, BslB);
        gld16(Bb + (size_t)(tr + 64) * NNODE + k0 + tc, BslB + 4096);
        __syncthreads();
        bf16x8 af[4], bf[4];
#pragma unroll
        for (int i = 0; i < 4; ++i)
            af[i] = *(const bf16x8*)&Asl[(wm + i * 16 + fr) * 32 + fk];
#pragma unroll
        for (int j = 0; j < 4; ++j)
            bf[j] = *(const bf16x8*)&Bsl[(wn + j * 16 + fr) * 32 + fk];
#pragma unroll
        for (int i = 0; i < 4; ++i)
#pragma unroll
            for (int j = 0; j < 4; ++j)
                acc[i][j] = __builtin_amdgcn_mfma_f32_16x16x32_bf16(af[i], bf[j], acc[i][j], 0, 0, 0);
        __syncthreads();
    }
    u16* Cb = C + sidx * csstr + (size_t)(blockIdx.y * 128 + wm) * ldc + blockIdx.x * 128 + wn;
    const int orow = (lane >> 4) * 4;
#pragma unroll
    for (int i = 0; i < 4; ++i)
#pragma unroll
        for (int j = 0; j < 4; ++j)
#pragma unroll
            for (int r = 0; r < 4; ++r)
                Cb[(size_t)(i * 16 + orow + r) * ldc + j * 16 + fr] = f2bf(acc[i][j][r]);
}

// ---- Z GEMM: Z[M x 4096] = xg[M x 2048] @ [S_a | S_b], a=2*pass, b=2*pass+1 ----
__global__ __launch_bounds__(256) void k_gemmZ(const u16* __restrict__ Xg,
                                               const u16* __restrict__ ST,
                                               u16* __restrict__ Z, int pass) {
    __shared__ u16 Asl[128 * 32];
    __shared__ u16 Bsl[128 * 32];
    const int tid = threadIdx.x;
    const int wave = tid >> 6, lane = tid & 63;
    const int m0 = blockIdx.y * 128;
    const int slice = pass * 2 + (blockIdx.x >> 4);
    const int nIn = (blockIdx.x & 15) * 128;
    const u16* Ab = Xg + (size_t)m0 * 2048;
    const u16* Bb = ST + (size_t)slice * SSTR + (size_t)nIn * NNODE;
    const int tr = tid >> 2;
    const int tc = (tid & 3) * 8;
    char* AslB = (char*)Asl + wave * 1024;
    char* BslB = (char*)Bsl + wave * 1024;
    const int wm = (wave & 1) * 64, wn = (wave >> 1) * 64;
    const int fr = lane & 15;
    const int fk = (lane >> 4) * 8;
    f32x4 acc[4][4];
#pragma unroll
    for (int i = 0; i < 4; ++i)
#pragma unroll
        for (int j = 0; j < 4; ++j) acc[i][j] = (f32x4){0.f, 0.f, 0.f, 0.f};

    for (int k0 = 0; k0 < 2048; k0 += 32) {
        gld16(Ab + (size_t)tr * 2048 + k0 + tc, AslB);
        gld16(Ab + (size_t)(tr + 64) * 2048 + k0 + tc, AslB + 4096);
        gld16(Bb + (size_t)tr * NNODE + k0 + tc, BslB);
        gld16(Bb + (size_t)(tr + 64) * NNODE + k0 + tc, BslB + 4096);
        __syncthreads();
        bf16x8 af[4], bf[4];
#pragma unroll
        for (int i = 0; i < 4; ++i)
            af[i] = *(const bf16x8*)&Asl[(wm + i * 16 + fr) * 32 + fk];
#pragma unroll
        for (int j = 0; j < 4; ++j)
            bf[j] = *(const bf16x8*)&Bsl[(wn + j * 16 + fr) * 32 + fk];
#pragma unroll
        for (int i = 0; i < 4; ++i)
#pragma unroll
            for (int j = 0; j < 4; ++j)
                acc[i][j] = __builtin_amdgcn_mfma_f32_16x16x32_bf16(af[i], bf[j], acc[i][j], 0, 0, 0);
        __syncthreads();
    }
    u16* Cb = Z + (size_t)(m0 + wm) * 4096 + blockIdx.x * 128 + wn;
    const int orow = (lane >> 4) * 4;
#pragma unroll
    for (int i = 0; i < 4; ++i)
#pragma unroll
        for (int j = 0; j < 4; ++j)
#pragma unroll
            for (int r = 0; r < 4; ++r)
                Cb[(size_t)(i * 16 + orow + r) * 4096 + j * 16 + fr] = f2bf(acc[i][j][r]);
}

// ---------------- start conv: pad t by 1, 2 -> 32 channels ----------------
__global__ __launch_bounds__(256) void k_start(const float* __restrict__ xin,
                                               const float* __restrict__ sw,
                                               const float* __restrict__ sb,
                                               float* __restrict__ out, int b0) {
    int n = blockIdx.x * 256 + threadIdx.x;
    int t = blockIdx.y;
    int bl = blockIdx.z;
    int b = b0 + bl;
    float x0 = 0.f, x1 = 0.f;
    if (t > 0) {
        x0 = xin[((size_t)(b * 2 + 0) * NNODE + n) * 12 + (t - 1)];
        x1 = xin[((size_t)(b * 2 + 1) * NNODE + n) * 12 + (t - 1)];
    }
#pragma unroll
    for (int co = 0; co < 32; ++co) {
        float v = sw[co * 2 + 0] * x0 + sw[co * 2 + 1] * x1 + sb[co];
        out[((size_t)(bl * 32 + co) * 13 + t) * NNODE + n] = v;
    }
}

// ------- fused dilated filter/gate conv + tanh*sigmoid -> bf16 xg -------
__global__ __launch_bounds__(256) void k_gate(const float* __restrict__ cur,
                                              u16* __restrict__ xg, int T, int Tn, int d,
                                              const float* __restrict__ fw,
                                              const float* __restrict__ fb,
                                              const float* __restrict__ gw,
                                              const float* __restrict__ gb) {
    __shared__ float4 wp[1024];  // [ci*32+co] = {fw0, fw1, gw0, gw1}
    int tid = threadIdx.x;
#pragma unroll
    for (int u = 0; u < 4; ++u) {
        int idx = tid + u * 256;
        int ci = idx >> 5, co = idx & 31;
        wp[idx] = make_float4(fw[co * 64 + ci * 2], fw[co * 64 + ci * 2 + 1],
                              gw[co * 64 + ci * 2], gw[co * 64 + ci * 2 + 1]);
    }
    __syncthreads();
    int n = blockIdx.x * 512 + tid;
    int t = blockIdx.y;
    int bl = blockIdx.z;
    float f0[32], f1[32], g0[32], g1[32];
#pragma unroll
    for (int co = 0; co < 32; ++co) { f0[co] = 0.f; f1[co] = 0.f; g0[co] = 0.f; g1[co] = 0.f; }
    for (int ci = 0; ci < 32; ++ci) {
        size_t ba = ((size_t)(bl * 32 + ci) * T + t) * NNODE + n;
        size_t bb = ((size_t)(bl * 32 + ci) * T + t + d) * NNODE + n;
        float xa0 = cur[ba], xa1 = cur[ba + 256];
        float xb0 = cur[bb], xb1 = cur[bb + 256];
#pragma unroll
        for (int co = 0; co < 32; ++co) {
            float4 w = wp[ci * 32 + co];
            f0[co] += w.x * xa0 + w.y * xb0;
            f1[co] += w.x * xa1 + w.y * xb1;
            g0[co] += w.z * xa0 + w.w * xb0;
            g1[co] += w.z * xa1 + w.w * xb1;
        }
    }
#pragma unroll
    for (int co = 0; co < 32; ++co) {
        float fbv = fb[co], gbv = gb[co];
        float a0 = tanhf(f0[co] + fbv) * (1.f / (1.f + expf(-(g0[co] + gbv))));
        float a1 = tanhf(f1[co] + fbv) * (1.f / (1.f + expf(-(g1[co] + gbv))));
        size_t o = ((size_t)(bl * 32 + co) * Tn + t) * NNODE + n;
        xg[o] = f2bf(a0);
        xg[o + 256] = f2bf(a1);
    }
}

// ---- skip conv, last time step only; accumulates across layers (f32) ----
__global__ __launch_bounds__(256) void k_skip(const u16* __restrict__ xg,
                                              float* __restrict__ skip, int Tn,
                                              const float* __restrict__ sw,
                                              const float* __restrict__ sb, int b0, int init) {
    __shared__ float wl[256];  // 8 sc rows x 32 ci
    int tid = threadIdx.x;
    int sc0 = blockIdx.y * 8;
    wl[tid] = sw[sc0 * 32 + tid];
    __syncthreads();
    int n = blockIdx.x * 256 + tid;
    int bl = blockIdx.z;
    float acc[8];
#pragma unroll
    for (int j = 0; j < 8; ++j) acc[j] = 0.f;
    for (int ci = 0; ci < 32; ci += 4) {
        float v0 = bf2f(xg[((size_t)(bl * 32 + ci + 0) * Tn + (Tn - 1)) * NNODE + n]);
        float v1 = bf2f(xg[((size_t)(bl * 32 + ci + 1) * Tn + (Tn - 1)) * NNODE + n]);
        float v2 = bf2f(xg[((size_t)(bl * 32 + ci + 2) * Tn + (Tn - 1)) * NNODE + n]);
        float v3 = bf2f(xg[((size_t)(bl * 32 + ci + 3) * Tn + (Tn - 1)) * NNODE + n]);
#pragma unroll
        for (int j = 0; j < 8; ++j) {
            float4 w = *(const float4*)&wl[j * 32 + ci];
            acc[j] += w.x * v0 + w.y * v1 + w.z * v2 + w.w * v3;
        }
    }
    int b = b0 + bl;
#pragma unroll
    for (int j = 0; j < 8; ++j) {
        size_t o = ((size_t)(b * 256) + sc0 + j) * NNODE + n;
        float val = acc[j] + sb[sc0 + j];
        if (init) skip[o] = val;
        else skip[o] += val;
    }
}

// ---- GCN mix+accumulate: nxt (+)= W0*xg + Wa*Z[:,0:2048] + Wb*Z[:,2048:] ----
// pass 0: init (gcn bias + identity group); pass 2: + resid, BN.
__global__ __launch_bounds__(256) void k_accum(const u16* __restrict__ xgp,
                                               const u16* __restrict__ Z,
                                               int c1, int c2,
                                               const float* __restrict__ gcnw,
                                               const float* __restrict__ gcnb,
                                               float* __restrict__ outp,
                                               const float* __restrict__ resid,
                                               int Tn, int d, int initf, int finalf,
                                               const float* __restrict__ bng,
                                               const float* __restrict__ bnb,
                                               const float* __restrict__ bnm,
                                               const float* __restrict__ bnv) {
    __shared__ float wl[3][32][32];  // [g][ci][co]
    int tid = threadIdx.x;
#pragma unroll
    for (int u = 0; u < 4; ++u) {
        int idx = tid + u * 256;
        int ci = idx >> 5, co = idx & 31;
        wl[0][ci][co] = gcnw[co * 224 + 0 + ci];
        wl[1][ci][co] = gcnw[co * 224 + c1 + ci];
        wl[2][ci][co] = gcnw[co * 224 + c2 + ci];
    }
    __syncthreads();
    int n = blockIdx.x * 512 + tid;  // n and n+256
    int t = blockIdx.y, bl = blockIdx.z;
    float a0[32], a1[32];
#pragma unroll
    for (int co = 0; co < 32; ++co) { a0[co] = 0.f; a1[co] = 0.f; }
    for (int ci = 0; ci < 32; ++ci) {
        size_t m = (size_t)(bl * 32 + ci) * Tn + t;
        if (xgp) {
            float v0 = bf2f(xgp[m * 2048 + n]), v1 = bf2f(xgp[m * 2048 + n + 256]);
#pragma unroll
            for (int cq = 0; cq < 8; ++cq) {
                float4 w = *(const float4*)&wl[0][ci][cq * 4];
                a0[cq * 4 + 0] += w.x * v0; a1[cq * 4 + 0] += w.x * v1;
                a0[cq * 4 + 1] += w.y * v0; a1[cq * 4 + 1] += w.y * v1;
                a0[cq * 4 + 2] += w.z * v0; a1[cq * 4 + 2] += w.z * v1;
                a0[cq * 4 + 3] += w.w * v0; a1[cq * 4 + 3] += w.w * v1;
            }
        }
        {
            float v0 = bf2f(Z[m * 4096 + n]), v1 = bf2f(Z[m * 4096 + n + 256]);
#pragma unroll
            for (int cq = 0; cq < 8; ++cq) {
                float4 w = *(const float4*)&wl[1][ci][cq * 4];
                a0[cq * 4 + 0] += w.x * v0; a1[cq * 4 + 0] += w.x * v1;
                a0[cq * 4 + 1] += w.y * v0; a1[cq * 4 + 1] += w.y * v1;
                a0[cq * 4 + 2] += w.z * v0; a1[cq * 4 + 2] += w.z * v1;
                a0[cq * 4 + 3] += w.w * v0; a1[cq * 4 + 3] += w.w * v1;
            }
        }
        {
            float v0 = bf2f(Z[m * 4096 + 2048 + n]), v1 = bf2f(Z[m * 4096 + 2048 + n + 256]);
#pragma unroll
            for (int cq = 0; cq < 8; ++cq) {
                float4 w = *(const float4*)&wl[2][ci][cq * 4];
                a0[cq * 4 + 0] += w.x * v0; a1[cq * 4 + 0] += w.x * v1;
                a0[cq * 4 + 1] += w.y * v0; a1[cq * 4 + 1] += w.y * v1;
                a0[cq * 4 + 2] += w.z * v0; a1[cq * 4 + 2] += w.z * v1;
                a0[cq * 4 + 3] += w.w * v0; a1[cq * 4 + 3] += w.w * v1;
            }
        }
    }
#pragma unroll
    for (int co = 0; co < 32; ++co) {
        size_t o = ((size_t)(bl * 32 + co) * Tn + t) * NNODE + n;
        float v0 = a0[co], v1 = a1[co];
        if (initf) {
            float bb = gcnb[co];
            v0 += bb; v1 += bb;
        } else {
            v0 += outp[o]; v1 += outp[o + 256];
        }
        if (finalf) {
            size_t ro = ((size_t)(bl * 32 + co) * (Tn + d) + t + d) * NNODE + n;
            v0 += resid[ro]; v1 += resid[ro + 256];
            float inv = bng[co] * rsqrtf(bnv[co] + 1e-5f);
            float mu = bnm[co], be = bnb[co];
            v0 = (v0 - mu) * inv + be;
            v1 = (v1 - mu) * inv + be;
        }
        outp[o] = v0; outp[o + 256] = v1;
    }
}

// ---- end head prep: skipT[b][n][sc] = bf16(relu(skip[b][sc][n])) ----
__global__ __launch_bounds__(256) void k_skipT(const float* __restrict__ skip,
                                               u16* __restrict__ skipT) {
    __shared__ float tile[32][33];
    int b = blockIdx.z;
    int n0 = blockIdx.x * 32, c0 = blockIdx.y * 32;
    int tx = threadIdx.x & 31, ty = threadIdx.x >> 5;
#pragma unroll
    for (int p = 0; p < 4; ++p)
        tile[ty + p * 8][tx] = skip[((size_t)b * 256 + c0 + ty + p * 8) * NNODE + n0 + tx];
    __syncthreads();
#pragma unroll
    for (int p = 0; p < 4; ++p)
        skipT[((size_t)b * NNODE + n0 + ty + p * 8) * 256 + c0 + tx] =
            f2bf(fmaxf(tile[tx][ty + p * 8], 0.f));
}

__global__ __launch_bounds__(256) void k_cast(const float* __restrict__ src,
                                              u16* __restrict__ dst) {
    int i = blockIdx.x * 256 + threadIdx.x;
    dst[i] = f2bf(src[i]);
}

// ---- end1 MFMA: h[b][e][n] = relu(E1[e,:] . relu(skip)[b,:,n] + b1[e]) ----
__global__ __launch_bounds__(256) void k_end1m(const u16* __restrict__ E1,
                                               const u16* __restrict__ skT,
                                               const float* __restrict__ bias,
                                               u16* __restrict__ h) {
    __shared__ u16 Asl[128 * 32];
    __shared__ u16 Bsl[128 * 32];
    const int tid = threadIdx.x;
    const int wave = tid >> 6, lane = tid & 63;
    const int b = blockIdx.z;
    const int m0 = blockIdx.y * 128;
    const int n0 = blockIdx.x * 128;
    const int tr = tid >> 2;
    const int tc = (tid & 3) * 8;
    char* AslB = (char*)Asl + wave * 1024;
    char* BslB = (char*)Bsl + wave * 1024;
    const int wm = (wave & 1) * 64, wn = (wave >> 1) * 64;
    const int fr = lane & 15;
    const int fk = (lane >> 4) * 8;
    const u16* Ab = E1 + (size_t)m0 * 256;
    const u16* Bb = skT + ((size_t)b * NNODE + n0) * 256;
    f32x4 acc[4][4];
#pragma unroll
    for (int i = 0; i < 4; ++i)
#pragma unroll
        for (int j = 0; j < 4; ++j) acc[i][j] = (f32x4){0.f, 0.f, 0.f, 0.f};
    for (int k0 = 0; k0 < 256; k0 += 32) {
        gld16(Ab + (size_t)tr * 256 + k0 + tc, AslB);
        gld16(Ab + (size_t)(tr + 64) * 256 + k0 + tc, AslB + 4096);
        gld16(Bb + (size_t)tr * 256 + k0 + tc, BslB);
        gld16(Bb + (size_t)(tr + 64) * 256 + k0 + tc, BslB + 4096);
        __syncthreads();
        bf16x8 af[4], bf[4];
#pragma unroll
        for (int i = 0; i < 4; ++i)
            af[i] = *(const bf16x8*)&Asl[(wm + i * 16 + fr) * 32 + fk];
#pragma unroll
        for (int j = 0; j < 4; ++j)
            bf[j] = *(const bf16x8*)&Bsl[(wn + j * 16 + fr) * 32 + fk];
#pragma unroll
        for (int i = 0; i < 4; ++i)
#pragma unroll
            for (int j = 0; j < 4; ++j)
                acc[i][j] = __builtin_amdgcn_mfma_f32_16x16x32_bf16(af[i], bf[j], acc[i][j], 0, 0, 0);
        __syncthreads();
    }
    const int orow = (lane >> 4) * 4;
#pragma unroll
    for (int i = 0; i < 4; ++i)
#pragma unroll
        for (int r = 0; r < 4; ++r) {
            int m = m0 + wm + i * 16 + orow + r;  // e index, < 512
            float bs = bias[m];
            size_t ob = ((size_t)b * 512 + m) * NNODE + n0 + wn;
#pragma unroll
            for (int j = 0; j < 4; ++j)
                h[ob + j * 16 + fr] = f2bf(fmaxf(acc[i][j][r] + bs, 0.f));
        }
}

__global__ __launch_bounds__(256) void k_end2(const u16* __restrict__ h,
                                              const float* __restrict__ w,
                                              const float* __restrict__ bias,
                                              float* __restrict__ out) {
    __shared__ float wl[512];
    int tid = threadIdx.x;
    int o = blockIdx.y;
    wl[tid] = w[o * 512 + tid];
    wl[tid + 256] = w[o * 512 + tid + 256];
    __syncthreads();
    int n = blockIdx.x * 256 + tid;
    int b = blockIdx.z;
    float acc = 0.f;
    for (int e = 0; e < 512; ++e) acc += wl[e] * bf2f(h[((size_t)(b * 512) + e) * NNODE + n]);
    out[((size_t)(b * 12) + o) * NNODE + n] = acc + bias[o];
}

extern "C" void kernel_launch(void* const* d_in, const int* in_sizes, int n_in,
                              void* d_out, int out_size, void* d_ws, size_t ws_size,
                              hipStream_t stream) {
    const float* x_in = (const float*)d_in[0];
    const float* A    = (const float*)d_in[1];
    const float* nv1  = (const float*)d_in[2];
    const float* nv2  = (const float*)d_in[3];
    const float* fw   = (const float*)d_in[4];
    const float* fb   = (const float*)d_in[5];
    const float* gw   = (const float*)d_in[6];
    const float* gb   = (const float*)d_in[7];
    const float* skw  = (const float*)d_in[8];
    const float* skb  = (const float*)d_in[9];
    const float* gcw  = (const float*)d_in[10];
    const float* gcb  = (const float*)d_in[11];
    const float* bng  = (const float*)d_in[12];
    const float* bnb  = (const float*)d_in[13];
    const float* bnm  = (const float*)d_in[14];
    const float* bnv  = (const float*)d_in[15];
    const float* stw  = (const float*)d_in[16];
    const float* stb  = (const float*)d_in[17];
    const float* e1w  = (const float*)d_in[18];
    const float* e1b  = (const float*)d_in[19];
    const float* e2w  = (const float*)d_in[20];
    const float* e2b  = (const float*)d_in[21];
    (void)in_sizes; (void)n_in; (void)out_size;

    // BL = batches per chunk. 16 needs exactly 256 MB; 8 needs 176,160,768 B
    // (proven in rounds 1-3). ws_size is constant across calls -> graph-safe.
    const int BL = (ws_size >= 268435456UL) ? 16 : 8;
    const int nch = 16 / BL;
    const size_t bufsz = (size_t)BL * 3407872UL;

    char* base = (char*)d_ws;
    u16*   ST   = (u16*)base;
    float* skip = (float*)(base + 50331648UL);
    float* bufA = (float*)(base + 83886080UL);
    float* bufB = (float*)(base + 83886080UL + bufsz);
    u16*   xg   = (u16*)(base + 83886080UL + 2 * bufsz);
    u16*   Z    = (u16*)(base + 83886080UL + 2 * bufsz + (size_t)BL * 1572864UL);
    // startup overlays
    float* adp  = (float*)Z;
    u16*   Sbf  = (u16*)bufA;
    // post-loop overlays
    u16*   h     = (u16*)bufA;   // spans bufA(+bufB)
    u16*   skipT = (u16*)xg;     // spans xg(+Z)
    u16*   E1bf  = (u16*)ST;

    k_adp_mm<<<dim3(8, 2048), 256, 0, stream>>>(nv1, nv2, adp);
    k_softmax<<<2048, 256, 0, stream>>>(adp);
    k_transp<<<dim3(64, 64, 3), 256, 0, stream>>>(A, adp, ST, Sbf);
    // (S_s^2)^T: A=S^T (slices 2s), BT=S (Sbf), C -> slices 2s+1
    k_gemm_mfma<<<dim3(16, 16, 3), 256, 0, stream>>>(
        ST, NNODE, 2 * SSTR, Sbf, SSTR, ST + SSTR, NNODE, 2 * SSTR, 0);

    static const int DIL[NLAYER] = {1, 2, 1, 2, 1, 2, 1, 2};
    for (int ch = 0; ch < nch; ++ch) {
        int b0 = ch * BL;
        k_start<<<dim3(8, 13, BL), 256, 0, stream>>>(x_in, stw, stb, bufA, b0);
        float* cur = bufA;
        float* nxt = bufB;
        int T = 13;
        for (int i = 0; i < NLAYER; ++i) {
            int d = DIL[i], Tn = T - d;
            k_gate<<<dim3(4, Tn, BL), 256, 0, stream>>>(cur, xg, T, Tn, d,
                fw + i * 2048, fb + i * 32, gw + i * 2048, gb + i * 32);
            k_skip<<<dim3(8, 32, BL), 256, 0, stream>>>(xg, skip, Tn,
                skw + i * 256 * 32, skb + i * 256, b0, (i == 0) ? 1 : 0);
            if (i == NLAYER - 1) break;  // layer 7's GCN output is dead
            int MB = BL * Tn / 4;        // M/128, M = BL*32*Tn
            const float* gcwi = gcw + i * 32 * 224;
            for (int p = 0; p < 3; ++p) {
                k_gemmZ<<<dim3(32, MB), 256, 0, stream>>>(xg, ST, Z, p);
                k_accum<<<dim3(4, Tn, BL), 256, 0, stream>>>(
                    (p == 0) ? xg : (const u16*)nullptr, Z,
                    32 + 64 * p, 64 + 64 * p,
                    gcwi, gcb + i * 32, nxt, cur, Tn, d,
                    (p == 0) ? 1 : 0, (p == 2) ? 1 : 0,
                    bng + i * 32, bnb + i * 32, bnm + i * 32, bnv + i * 32);
            }
            float* tmp = cur; cur = nxt; nxt = tmp;
            T = Tn;
        }
    }
    k_cast<<<512, 256, 0, stream>>>(e1w, E1bf);
    k_skipT<<<dim3(64, 8, 16), 256, 0, stream>>>(skip, skipT);
    k_end1m<<<dim3(16, 4, 16), 256, 0, stream>>>(E1bf, skipT, e1b, h);
    k_end2<<<dim3(8, 12, 16), 256, 0, stream>>>(h, e2w, e2b, (float*)d_out);
}